// Round 1
// baseline (720.871 us; speedup 1.0000x reference)
//
#include <hip/hip_runtime.h>
#include <hip/hip_bf16.h>
#include <stdint.h>
#include <math.h>

#define BB 4
#define NN 2048
#define NFEAT 256
#define NHID 64
#define NHEADS 4
#define NCLASS 32
#define KK1 256
#define ALPHA 0.2f

__device__ __forceinline__ float lrelu(float x){ return fmaxf(x, ALPHA*x); }

__device__ __forceinline__ float wave_reduce_sum(float v){
  #pragma unroll
  for (int o=32;o>0;o>>=1) v += __shfl_xor(v,o,64);
  return v;
}

// ---------------- K0: pack adj int32 -> bitmask -------------------------
__global__ void __launch_bounds__(256) pack_adj(const int* __restrict__ adj,
                                                unsigned long long* __restrict__ bits){
  int row = blockIdx.x;                       // b*N + i
  const int* arow = adj + (size_t)row * NN;
  int lane = threadIdx.x & 63, wv = threadIdx.x >> 6;
  #pragma unroll
  for (int it=0; it<NN/256; ++it){
    int j = it*256 + threadIdx.x;
    unsigned long long m = __ballot(arow[j] > 0);
    if (lane==0) bits[(size_t)row*(NN/64) + it*4 + wv] = m;
  }
}

// ---------------- K1: Wh = x @ W per head, plus f1/f2 -------------------
__global__ void __launch_bounds__(256) wh_proj(const float* __restrict__ x,
        const float* __restrict__ W, const float* __restrict__ a1, const float* __restrict__ a2,
        float* __restrict__ Wh, float* __restrict__ f1, float* __restrict__ f2){
  __shared__ __align__(16) float xs[4*NFEAT];
  int blk = blockIdx.x;
  int bh = blk >> 9;                // / (N/4 = 512)
  int i0 = (blk & 511) * 4;
  int b = bh >> 2, h = bh & 3;
  ((float4*)xs)[threadIdx.x] = ((const float4*)(x + ((size_t)(b*NN + i0))*NFEAT))[threadIdx.x];
  __syncthreads();
  int lane = threadIdx.x & 63, r = threadIdx.x >> 6;
  const float* Wp = W + ((size_t)h)*NFEAT*NHID + lane;
  const float* xr = xs + r*NFEAT;
  float acc = 0.f;
  #pragma unroll 8
  for (int f=0; f<NFEAT; ++f) acc += xr[f] * Wp[(size_t)f*NHID];
  int i = i0 + r;
  Wh[((size_t)bh*NN + i)*NHID + lane] = acc;
  float v1 = wave_reduce_sum(acc * a1[h*NHID + lane]);
  float v2 = wave_reduce_sum(acc * a2[h*NHID + lane]);
  if (lane==0){ f1[(size_t)bh*NN + i] = v1; f2[(size_t)bh*NN + i] = v2; }
}

// ---------------- K2a/K3b: per-row softmax stats (max, sumexp) ----------
template<int NH>
__global__ void __launch_bounds__(256) attn_stats(const unsigned long long* __restrict__ bits,
        const float* __restrict__ f1, const float* __restrict__ f2,
        float* __restrict__ m_out, float* __restrict__ l_out, int* __restrict__ cnt_out){
  int row = blockIdx.x*4 + (threadIdx.x>>6);  // b*N + i
  int lane = threadIdx.x & 63;
  int b = row >> 11;
  int i = row & (NN-1);
  const unsigned long long* wrow = bits + (size_t)row*(NN/64);
  float f1v[NH], mx[NH];
  #pragma unroll
  for (int h=0;h<NH;++h){
    f1v[h] = f1[((size_t)(b*NH+h))*NN + i];
    mx[h] = -INFINITY;
  }
  int cnt = 0;
  for (int it=0; it<NN/64; ++it){
    unsigned long long w = wrow[it];
    cnt += __popcll(w);
    bool bit = (w >> lane) & 1ull;
    int j = it*64 + lane;
    #pragma unroll
    for (int h=0;h<NH;++h){
      float v = f2[((size_t)(b*NH+h))*NN + j];
      if (bit) mx[h] = fmaxf(mx[h], v);
    }
  }
  #pragma unroll
  for (int h=0;h<NH;++h){
    #pragma unroll
    for (int o=32;o>0;o>>=1) mx[h] = fmaxf(mx[h], __shfl_xor(mx[h], o, 64));
  }
  float m[NH], ls[NH];
  #pragma unroll
  for (int h=0;h<NH;++h){ m[h] = lrelu(f1v[h] + mx[h]); ls[h] = 0.f; }
  for (int it=0; it<NN/64; ++it){
    unsigned long long w = wrow[it];
    bool bit = (w >> lane) & 1ull;
    int j = it*64 + lane;
    #pragma unroll
    for (int h=0;h<NH;++h){
      float e = lrelu(f1v[h] + f2[((size_t)(b*NH+h))*NN + j]);
      if (bit) ls[h] += __expf(e - m[h]);
    }
  }
  #pragma unroll
  for (int h=0;h<NH;++h) ls[h] = wave_reduce_sum(ls[h]);
  if (lane==0){
    cnt_out[row] = cnt;
    #pragma unroll
    for (int h=0;h<NH;++h){
      size_t o = ((size_t)(b*NH+h))*NN + i;
      if (cnt==0){ m_out[o]=0.f; l_out[o]=(float)NN; }
      else       { m_out[o]=m[h]; l_out[o]=ls[h]; }
    }
  }
}

// ---------------- K2b/K3c: out = softmax(e) @ Wh, then ELU --------------
// block = 256 thr (4 waves), 32 rows/block (8 per wave), j tiled by 64.
template<int D>
__global__ void __launch_bounds__(256) attn_wsum(const unsigned long long* __restrict__ bits,
        const float* __restrict__ Whp, const float* __restrict__ f1, const float* __restrict__ f2,
        const float* __restrict__ m_in, const float* __restrict__ l_in, const int* __restrict__ cnt_in,
        float* __restrict__ dst, int H, int dstStride){
  __shared__ __align__(16) float whs[64*D];
  __shared__ __align__(16) float wts[32*64];
  __shared__ float f2s[64];
  __shared__ unsigned long long aw[32];
  int blk = blockIdx.x;
  int tile = blk & 63;              // N/32 = 64 tiles
  int bh = blk >> 6;
  int b = bh / H, h = bh - b*H;
  int i0 = tile*32;
  int lane = threadIdx.x & 63, wv = threadIdx.x >> 6;
  float f1r[8], mr[8], ilr[8];
  bool cz[8];
  #pragma unroll
  for (int rr=0; rr<8; ++rr){
    int i = i0 + wv*8 + rr;
    size_t o = (size_t)bh*NN + i;
    f1r[rr] = f1[o]; mr[rr] = m_in[o]; ilr[rr] = 1.0f/l_in[o];
    cz[rr] = (cnt_in[b*NN + i] == 0);
  }
  float acc[8];
  #pragma unroll
  for (int rr=0; rr<8; ++rr) acc[rr] = 0.f;
  const float4* src4 = (const float4*)(Whp + (size_t)bh*NN*D);
  int dl = lane & (D-1);
  for (int it=0; it<NN/64; ++it){
    __syncthreads();
    #pragma unroll
    for (int t=0; t<(64*D)/(4*256); ++t){
      int idx = t*256 + threadIdx.x;
      ((float4*)whs)[idx] = src4[(size_t)it*(64*D/4) + idx];
    }
    if (threadIdx.x < 64) f2s[threadIdx.x] = f2[(size_t)bh*NN + it*64 + threadIdx.x];
    if (threadIdx.x < 32) aw[threadIdx.x] = bits[((size_t)(b*NN + i0 + threadIdx.x))*(NN/64) + it];
    __syncthreads();
    // weights: lane = j within chunk; each wave fills its own 8 rows
    #pragma unroll
    for (int rr=0; rr<8; ++rr){
      int r = wv*8 + rr;
      float s = f1r[rr] + f2s[lane];
      float e = fmaxf(s, ALPHA*s);
      bool bit = (aw[r] >> lane) & 1ull;
      float wgt = cz[rr] ? 1.0f : (bit ? __expf(e - mr[rr]) : 0.f);
      wts[r*64 + lane] = wgt;
    }
    // accumulate: lane = d
    #pragma unroll 4
    for (int j4=0; j4<16; ++j4){
      float w0 = whs[(j4*4+0)*D + dl];
      float w1 = whs[(j4*4+1)*D + dl];
      float w2 = whs[(j4*4+2)*D + dl];
      float w3 = whs[(j4*4+3)*D + dl];
      #pragma unroll
      for (int rr=0; rr<8; ++rr){
        float4 ww = *(const float4*)&wts[(wv*8+rr)*64 + j4*4];
        acc[rr] += ww.x*w0;
        acc[rr] += ww.y*w1;
        acc[rr] += ww.z*w2;
        acc[rr] += ww.w*w3;
      }
    }
  }
  #pragma unroll
  for (int rr=0; rr<8; ++rr){
    int i = i0 + wv*8 + rr;
    float o = acc[rr]*ilr[rr];
    o = o > 0.f ? o : expm1f(o);       // ELU (both layers apply it)
    if (lane < D) dst[((size_t)b*NN + i)*dstStride + h*D + lane] = o;
  }
}

// ---------------- K3a: Wh2 = h1 @ Wo, plus f1o/f2o ----------------------
__global__ void __launch_bounds__(256) out_proj(const float* __restrict__ h1,
        const float* __restrict__ Wo, const float* __restrict__ ao1, const float* __restrict__ ao2,
        float* __restrict__ Wh2, float* __restrict__ f1o, float* __restrict__ f2o){
  __shared__ __align__(16) float hs[4*256];
  int i0 = blockIdx.x*4;            // global row over b*N
  ((float4*)hs)[threadIdx.x] = ((const float4*)(h1 + (size_t)i0*256))[threadIdx.x];
  __syncthreads();
  int lane = threadIdx.x & 63, r = threadIdx.x >> 6;
  int c = lane & 31, kh = lane >> 5;
  const float* hr = hs + r*256 + kh*128;
  float acc = 0.f;
  #pragma unroll 8
  for (int f=0; f<128; ++f) acc += hr[f] * Wo[(kh*128+f)*32 + c];
  acc += __shfl_xor(acc, 32, 64);   // fold the two K-halves
  int row = i0 + r;
  float t1 = acc * ao1[c];
  float t2 = acc * ao2[c];
  #pragma unroll
  for (int o=16;o>0;o>>=1){ t1 += __shfl_xor(t1,o,64); t2 += __shfl_xor(t2,o,64); }
  if (lane < 32) Wh2[(size_t)row*32 + c] = acc;
  if (lane == 0){ f1o[row] = t1; f2o[row] = t2; }
}

// ---------------- K4: gather + Linear + PReLU + Linear ------------------
__global__ void __launch_bounds__(256) classify(const float* __restrict__ h2,
        const int* __restrict__ idcs, const float* __restrict__ W1, const float* __restrict__ b1,
        const float* __restrict__ pw, const float* __restrict__ W2, const float* __restrict__ b2,
        float* __restrict__ out){
  int row = blockIdx.x*4 + (threadIdx.x>>6);  // 0..B*K1-1
  int lane = threadIdx.x & 63;
  int b = row >> 8;                 // K1 = 256
  int k = row & 255;
  int idx = idcs[b*KK1 + k];
  const float* ef = h2 + ((size_t)b*NN + idx)*32;
  int c = lane & 31;
  float y = b1[c];
  #pragma unroll 8
  for (int kk=0; kk<32; ++kk) y += ef[kk] * W1[kk*32 + c];
  y = y > 0.f ? y : pw[c]*y;        // PReLU
  float o0 = y * W2[c*2+0];
  float o1 = y * W2[c*2+1];
  #pragma unroll
  for (int o=16;o>0;o>>=1){ o0 += __shfl_xor(o0,o,64); o1 += __shfl_xor(o1,o,64); }
  if (lane==0){ out[row*2+0] = o0 + b2[0]; out[row*2+1] = o1 + b2[1]; }
}

extern "C" void kernel_launch(void* const* d_in, const int* in_sizes, int n_in,
                              void* d_out, int out_size, void* d_ws, size_t ws_size,
                              hipStream_t stream) {
  const float* x    = (const float*)d_in[0];
  const int*   adj  = (const int*)  d_in[1];
  const int*   oh   = (const int*)  d_in[2];
  const float* W    = (const float*)d_in[3];
  const float* a1   = (const float*)d_in[4];
  const float* a2   = (const float*)d_in[5];
  const float* Wo   = (const float*)d_in[6];
  const float* ao1  = (const float*)d_in[7];
  const float* ao2  = (const float*)d_in[8];
  const float* W1   = (const float*)d_in[9];
  const float* b1   = (const float*)d_in[10];
  const float* pw   = (const float*)d_in[11];
  const float* W2   = (const float*)d_in[12];
  const float* b2   = (const float*)d_in[13];
  float* out = (float*)d_out;

  char* base = (char*)d_ws;
  size_t off = 0;
  auto alloc = [&](size_t bytes)->char*{
    char* p = base + off;
    off = (off + bytes + 255) & ~(size_t)255;
    return p;
  };
  unsigned long long* adjbits = (unsigned long long*)alloc((size_t)BB*NN*(NN/64)*8); // 2 MB
  float* Wh   = (float*)alloc((size_t)BB*NHEADS*NN*NHID*4);   // 8 MB
  float* f1   = (float*)alloc((size_t)BB*NHEADS*NN*4);
  float* f2   = (float*)alloc((size_t)BB*NHEADS*NN*4);
  float* m1   = (float*)alloc((size_t)BB*NHEADS*NN*4);
  float* l1   = (float*)alloc((size_t)BB*NHEADS*NN*4);
  int*   cnt1 = (int*)  alloc((size_t)BB*NN*4);
  float* h1   = (float*)alloc((size_t)BB*NN*(NHEADS*NHID)*4); // 8 MB
  float* Wh2  = (float*)alloc((size_t)BB*NN*NCLASS*4);        // 1 MB
  float* f1o  = (float*)alloc((size_t)BB*NN*4);
  float* f2o  = (float*)alloc((size_t)BB*NN*4);
  float* m2   = (float*)alloc((size_t)BB*NN*4);
  float* l2   = (float*)alloc((size_t)BB*NN*4);
  int*   cnt2 = (int*)  alloc((size_t)BB*NN*4);
  float* h2   = (float*)alloc((size_t)BB*NN*NCLASS*4);        // 1 MB

  pack_adj<<<BB*NN, 256, 0, stream>>>(adj, adjbits);
  wh_proj<<<BB*NHEADS*(NN/4), 256, 0, stream>>>(x, W, a1, a2, Wh, f1, f2);
  attn_stats<NHEADS><<<(BB*NN)/4, 256, 0, stream>>>(adjbits, f1, f2, m1, l1, cnt1);
  attn_wsum<64><<<BB*NHEADS*(NN/32), 256, 0, stream>>>(adjbits, Wh, f1, f2, m1, l1, cnt1,
                                                       h1, NHEADS, NHEADS*NHID);
  out_proj<<<(BB*NN)/4, 256, 0, stream>>>(h1, Wo, ao1, ao2, Wh2, f1o, f2o);
  attn_stats<1><<<(BB*NN)/4, 256, 0, stream>>>(adjbits, f1o, f2o, m2, l2, cnt2);
  attn_wsum<32><<<BB*(NN/32), 256, 0, stream>>>(adjbits, Wh2, f1o, f2o, m2, l2, cnt2,
                                                h2, 1, NCLASS);
  classify<<<(BB*KK1)/4, 256, 0, stream>>>(h2, oh, W1, b1, pw, W2, b2, out);
}

// Round 2
// 367.665 us; speedup vs baseline: 1.9607x; 1.9607x over previous
//
#include <hip/hip_runtime.h>
#include <hip/hip_bf16.h>
#include <stdint.h>
#include <math.h>

#define BB 4
#define NN 2048
#define NFEAT 256
#define NHID 64
#define NHEADS 4
#define NCLASS 32
#define KK1 256
#define ALPHA 0.2f

typedef _Float16 f16x8 __attribute__((ext_vector_type(8)));
typedef _Float16 f16x4 __attribute__((ext_vector_type(4)));
typedef float f32x4 __attribute__((ext_vector_type(4)));

__device__ __forceinline__ float lrelu(float x){ return fmaxf(x, ALPHA*x); }

__device__ __forceinline__ f16x8 ld8(const _Float16* p){
  f16x8 r;
  *(f16x4*)&r = *(const f16x4*)p;
  *((f16x4*)&r + 1) = *(const f16x4*)(p + 4);
  return r;
}

__device__ __forceinline__ float wave_reduce_sum(float v){
  #pragma unroll
  for (int o=32;o>0;o>>=1) v += __shfl_xor(v,o,64);
  return v;
}

// ---------------- K0: pack adj int32 -> bitmask -------------------------
__global__ void __launch_bounds__(256) pack_adj(const int* __restrict__ adj,
                                                unsigned long long* __restrict__ bits){
  int row = blockIdx.x;                       // b*N + i
  const int* arow = adj + (size_t)row * NN;
  int lane = threadIdx.x & 63, wv = threadIdx.x >> 6;
  #pragma unroll
  for (int it=0; it<NN/256; ++it){
    int j = it*256 + threadIdx.x;
    unsigned long long m = __ballot(arow[j] > 0);
    if (lane==0) bits[(size_t)row*(NN/64) + it*4 + wv] = m;
  }
}

// ---------------- K1: WhT(f16) = (x @ W)^T per head, plus f1/f2 ---------
// block = (bh, 64-row i-chunk). lane = i, wave w owns d-range w*16..+16.
__global__ void __launch_bounds__(256) wh_proj2(const float* __restrict__ x,
        const float* __restrict__ W, const float* __restrict__ a1, const float* __restrict__ a2,
        _Float16* __restrict__ whT, float* __restrict__ f1, float* __restrict__ f2){
  __shared__ __align__(16) float xs[64*65];
  __shared__ float red1[4][64];
  __shared__ float red2[4][64];
  int bh = blockIdx.x >> 5;
  int i0 = (blockIdx.x & 31) * 64;
  int b = bh >> 2, h = bh & 3;
  int tid = threadIdx.x;
  int lane = tid & 63;
  int dbase = __builtin_amdgcn_readfirstlane(tid >> 6) * 16;
  float acc[16];
  #pragma unroll
  for (int dd=0; dd<16; ++dd) acc[dd] = 0.f;
  for (int kc=0; kc<4; ++kc){
    int kb = kc*64;
    __syncthreads();
    #pragma unroll
    for (int t=0; t<4; ++t){
      int row = t*16 + (tid>>4);
      int f4 = (tid&15)*4;
      float4 v = *(const float4*)(x + ((size_t)(b*NN + i0 + row))*NFEAT + kb + f4);
      xs[row*65 + f4 + 0] = v.x;
      xs[row*65 + f4 + 1] = v.y;
      xs[row*65 + f4 + 2] = v.z;
      xs[row*65 + f4 + 3] = v.w;
    }
    __syncthreads();
    const float* Wb = W + (size_t)h*NFEAT*NHID + (size_t)kb*NHID + dbase;
    #pragma unroll 4
    for (int f=0; f<64; ++f){
      float xv = xs[lane*65 + f];
      const float* wr = Wb + f*NHID;
      #pragma unroll
      for (int dd=0; dd<16; ++dd) acc[dd] = fmaf(xv, wr[dd], acc[dd]);
    }
  }
  // epilogue: transposed f16 store + f1/f2 partials
  float p1 = 0.f, p2 = 0.f;
  #pragma unroll
  for (int dd=0; dd<16; ++dd){
    int d = dbase + dd;
    whT[((size_t)bh*NHID + d)*NN + i0 + lane] = (_Float16)acc[dd];
    p1 = fmaf(acc[dd], a1[h*NHID + d], p1);
    p2 = fmaf(acc[dd], a2[h*NHID + d], p2);
  }
  int wv = tid >> 6;
  red1[wv][lane] = p1;
  red2[wv][lane] = p2;
  __syncthreads();
  if (tid < 64){
    float s1 = red1[0][tid]+red1[1][tid]+red1[2][tid]+red1[3][tid];
    float s2 = red2[0][tid]+red2[1][tid]+red2[2][tid]+red2[3][tid];
    f1[(size_t)bh*NN + i0 + tid] = s1;
    f2[(size_t)bh*NN + i0 + tid] = s2;
  }
}

// ---------------- K2a/K3b: per-row softmax stats (max, sumexp) ----------
template<int NH>
__global__ void __launch_bounds__(256) attn_stats(const unsigned long long* __restrict__ bits,
        const float* __restrict__ f1, const float* __restrict__ f2,
        float* __restrict__ m_out, float* __restrict__ l_out, int* __restrict__ cnt_out){
  int row = blockIdx.x*4 + (threadIdx.x>>6);  // b*N + i
  int lane = threadIdx.x & 63;
  int b = row >> 11;
  int i = row & (NN-1);
  const unsigned long long* wrow = bits + (size_t)row*(NN/64);
  float f1v[NH], mx[NH];
  #pragma unroll
  for (int h=0;h<NH;++h){
    f1v[h] = f1[((size_t)(b*NH+h))*NN + i];
    mx[h] = -INFINITY;
  }
  int cnt = 0;
  for (int it=0; it<NN/64; ++it){
    unsigned long long w = wrow[it];
    cnt += __popcll(w);
    bool bit = (w >> lane) & 1ull;
    int j = it*64 + lane;
    #pragma unroll
    for (int h=0;h<NH;++h){
      float v = f2[((size_t)(b*NH+h))*NN + j];
      if (bit) mx[h] = fmaxf(mx[h], v);
    }
  }
  #pragma unroll
  for (int h=0;h<NH;++h){
    #pragma unroll
    for (int o=32;o>0;o>>=1) mx[h] = fmaxf(mx[h], __shfl_xor(mx[h], o, 64));
  }
  float m[NH], ls[NH];
  #pragma unroll
  for (int h=0;h<NH;++h){ m[h] = lrelu(f1v[h] + mx[h]); ls[h] = 0.f; }
  for (int it=0; it<NN/64; ++it){
    unsigned long long w = wrow[it];
    bool bit = (w >> lane) & 1ull;
    int j = it*64 + lane;
    #pragma unroll
    for (int h=0;h<NH;++h){
      float e = lrelu(f1v[h] + f2[((size_t)(b*NH+h))*NN + j]);
      if (bit) ls[h] += __expf(e - m[h]);
    }
  }
  #pragma unroll
  for (int h=0;h<NH;++h) ls[h] = wave_reduce_sum(ls[h]);
  if (lane==0){
    cnt_out[row] = cnt;
    #pragma unroll
    for (int h=0;h<NH;++h){
      size_t o = ((size_t)(b*NH+h))*NN + i;
      if (cnt==0){ m_out[o]=0.f; l_out[o]=(float)NN; }
      else       { m_out[o]=m[h]; l_out[o]=ls[h]; }
    }
  }
}

// ---------------- K2b/K3c: dst = elu(softmax(e) @ Wh)  via f16 MFMA -----
// M=32 rows/block, K-chunk=64 j. whT is f16 [bh][D][N] (pre-transposed).
// D=64: wave w -> N-tile w (16 cols), computes 2 M-tiles.
// D=32: wave w -> (mt=w&1, nt=w>>1), 1 MFMA.
template<int D>
__global__ void __launch_bounds__(256) attn_wsum_mfma(
        const unsigned long long* __restrict__ bits,
        const _Float16* __restrict__ whT,
        const float* __restrict__ f1g, const float* __restrict__ f2g,
        const float* __restrict__ m_in, const float* __restrict__ l_in,
        const int* __restrict__ cnt_in,
        float* __restrict__ dst, int H, int dstStride){
  const int PITCH = 68;                         // f16 pitch for 64-j chunk
  __shared__ __align__(16) _Float16 whsT[D*PITCH];
  __shared__ __align__(16) _Float16 wts[32*PITCH];
  __shared__ float ils[32];
  int tile = blockIdx.x & 63;
  int bh = blockIdx.x >> 6;
  int b = bh / H, h = bh - b*H;
  int i0 = tile*32;
  int tid = threadIdx.x;
  int lane = tid & 63, wv = tid >> 6;
  int q = lane >> 4, col = lane & 15;
  // weight-phase mapping: 8 threads per row
  int r = tid >> 3;                             // 0..31
  int j8 = (tid & 7) * 8;
  size_t ro = (size_t)bh*NN + i0 + r;
  float f1r = f1g[ro];
  float mr  = m_in[ro];
  bool  czr = (cnt_in[b*NN + i0 + r] == 0);
  if (tid < 32) ils[tid] = 1.0f / l_in[(size_t)bh*NN + i0 + tid];
  const _Float16* whTg = whT + (size_t)bh*D*NN;
  f32x4 c0 = {0.f,0.f,0.f,0.f}, c1 = {0.f,0.f,0.f,0.f};
  for (int it=0; it<NN/64; ++it){
    __syncthreads();
    // stage B: whsT[d][j] (transposed Wh, f16) from global
    #pragma unroll
    for (int dd=0; dd<D/32; ++dd){
      int d = dd*32 + (tid>>3);
      uint4 v = *(const uint4*)(whTg + (size_t)d*NN + it*64 + j8);
      uint2* dst2 = (uint2*)&whsT[d*PITCH + j8];
      dst2[0] = uint2{v.x, v.y};
      dst2[1] = uint2{v.z, v.w};
    }
    // stage A: weights for 32 rows x 64 j
    {
      unsigned long long bw = bits[((size_t)(b*NN + i0 + r))*(NN/64) + it];
      const float* f2p = f2g + (size_t)bh*NN + it*64 + j8;
      float4 fa = *(const float4*)(f2p);
      float4 fb = *(const float4*)(f2p + 4);
      float fv[8] = {fa.x,fa.y,fa.z,fa.w,fb.x,fb.y,fb.z,fb.w};
      _Float16 wf[8];
      #pragma unroll
      for (int k=0; k<8; ++k){
        float s = f1r + fv[k];
        float e = fmaxf(s, ALPHA*s);
        bool bit = (bw >> (j8 + k)) & 1ull;
        float w = czr ? 1.0f : (bit ? __expf(e - mr) : 0.0f);
        wf[k] = (_Float16)w;
      }
      f16x4* wp = (f16x4*)&wts[r*PITCH + j8];
      wp[0] = f16x4{wf[0],wf[1],wf[2],wf[3]};
      wp[1] = f16x4{wf[4],wf[5],wf[6],wf[7]};
    }
    __syncthreads();
    // MFMA phase: 2 K-steps of 32
    #pragma unroll
    for (int ks=0; ks<2; ++ks){
      int kb = ks*32 + q*8;
      if (D == 64){
        f16x8 a0 = ld8(&wts[(0*16 + col)*PITCH + kb]);
        f16x8 a1f = ld8(&wts[(1*16 + col)*PITCH + kb]);
        f16x8 bf = ld8(&whsT[(wv*16 + col)*PITCH + kb]);
        c0 = __builtin_amdgcn_mfma_f32_16x16x32_f16(a0, bf, c0, 0, 0, 0);
        c1 = __builtin_amdgcn_mfma_f32_16x16x32_f16(a1f, bf, c1, 0, 0, 0);
      } else {
        int mt = wv & 1, nt = wv >> 1;
        f16x8 a0 = ld8(&wts[(mt*16 + col)*PITCH + kb]);
        f16x8 bf = ld8(&whsT[(nt*16 + col)*PITCH + kb]);
        c0 = __builtin_amdgcn_mfma_f32_16x16x32_f16(a0, bf, c0, 0, 0, 0);
      }
    }
  }
  // epilogue: scale by 1/l, ELU, store
  if (D == 64){
    int dloc = wv*16 + col;
    #pragma unroll
    for (int mt=0; mt<2; ++mt){
      #pragma unroll
      for (int reg=0; reg<4; ++reg){
        int ir = mt*16 + q*4 + reg;
        float v = (mt==0 ? c0[reg] : c1[reg]) * ils[ir];
        v = v > 0.f ? v : expm1f(v);
        dst[((size_t)(b*NN + i0 + ir))*dstStride + h*D + dloc] = v;
      }
    }
  } else {
    int mt = wv & 1, nt = wv >> 1;
    int dloc = nt*16 + col;
    #pragma unroll
    for (int reg=0; reg<4; ++reg){
      int ir = mt*16 + q*4 + reg;
      float v = c0[reg] * ils[ir];
      v = v > 0.f ? v : expm1f(v);
      dst[((size_t)(b*NN + i0 + ir))*dstStride + h*D + dloc] = v;
    }
  }
}

// ---------------- K3a: Wh2T(f16) = (h1 @ Wo)^T, plus f1o/f2o ------------
__global__ void __launch_bounds__(256) out_proj2(const float* __restrict__ h1,
        const float* __restrict__ Wo, const float* __restrict__ ao1, const float* __restrict__ ao2,
        _Float16* __restrict__ whT2, float* __restrict__ f1o, float* __restrict__ f2o){
  __shared__ __align__(16) float xs[64*65];
  __shared__ float red1[4][64];
  __shared__ float red2[4][64];
  int b = blockIdx.x >> 5;
  int i0 = (blockIdx.x & 31) * 64;
  int tid = threadIdx.x;
  int lane = tid & 63;
  int dbase = __builtin_amdgcn_readfirstlane(tid >> 6) * 8;
  float acc[8];
  #pragma unroll
  for (int dd=0; dd<8; ++dd) acc[dd] = 0.f;
  for (int kc=0; kc<4; ++kc){
    int kb = kc*64;
    __syncthreads();
    #pragma unroll
    for (int t=0; t<4; ++t){
      int row = t*16 + (tid>>4);
      int f4 = (tid&15)*4;
      float4 v = *(const float4*)(h1 + ((size_t)(b*NN + i0 + row))*256 + kb + f4);
      xs[row*65 + f4 + 0] = v.x;
      xs[row*65 + f4 + 1] = v.y;
      xs[row*65 + f4 + 2] = v.z;
      xs[row*65 + f4 + 3] = v.w;
    }
    __syncthreads();
    #pragma unroll 4
    for (int f=0; f<64; ++f){
      float xv = xs[lane*65 + f];
      const float* wr = Wo + (size_t)(kb+f)*NCLASS + dbase;
      #pragma unroll
      for (int dd=0; dd<8; ++dd) acc[dd] = fmaf(xv, wr[dd], acc[dd]);
    }
  }
  float p1 = 0.f, p2 = 0.f;
  #pragma unroll
  for (int dd=0; dd<8; ++dd){
    int d = dbase + dd;
    whT2[((size_t)b*NCLASS + d)*NN + i0 + lane] = (_Float16)acc[dd];
    p1 = fmaf(acc[dd], ao1[d], p1);
    p2 = fmaf(acc[dd], ao2[d], p2);
  }
  int wv = tid >> 6;
  red1[wv][lane] = p1;
  red2[wv][lane] = p2;
  __syncthreads();
  if (tid < 64){
    float s1 = red1[0][tid]+red1[1][tid]+red1[2][tid]+red1[3][tid];
    float s2 = red2[0][tid]+red2[1][tid]+red2[2][tid]+red2[3][tid];
    f1o[(size_t)b*NN + i0 + tid] = s1;
    f2o[(size_t)b*NN + i0 + tid] = s2;
  }
}

// ---------------- K4: gather + Linear + PReLU + Linear ------------------
__global__ void __launch_bounds__(256) classify(const float* __restrict__ h2,
        const int* __restrict__ idcs, const float* __restrict__ W1, const float* __restrict__ b1,
        const float* __restrict__ pw, const float* __restrict__ W2, const float* __restrict__ b2,
        float* __restrict__ out){
  int row = blockIdx.x*4 + (threadIdx.x>>6);  // 0..B*K1-1
  int lane = threadIdx.x & 63;
  int b = row >> 8;                 // K1 = 256
  int k = row & 255;
  int idx = idcs[b*KK1 + k];
  const float* ef = h2 + ((size_t)b*NN + idx)*NCLASS;
  int c = lane & 31;
  float y = b1[c];
  #pragma unroll 8
  for (int kk=0; kk<32; ++kk) y += ef[kk] * W1[kk*32 + c];
  y = y > 0.f ? y : pw[c]*y;        // PReLU
  float o0 = y * W2[c*2+0];
  float o1 = y * W2[c*2+1];
  #pragma unroll
  for (int o=16;o>0;o>>=1){ o0 += __shfl_xor(o0,o,64); o1 += __shfl_xor(o1,o,64); }
  if (lane==0){ out[row*2+0] = o0 + b2[0]; out[row*2+1] = o1 + b2[1]; }
}

extern "C" void kernel_launch(void* const* d_in, const int* in_sizes, int n_in,
                              void* d_out, int out_size, void* d_ws, size_t ws_size,
                              hipStream_t stream) {
  const float* x    = (const float*)d_in[0];
  const int*   adj  = (const int*)  d_in[1];
  const int*   oh   = (const int*)  d_in[2];
  const float* W    = (const float*)d_in[3];
  const float* a1   = (const float*)d_in[4];
  const float* a2   = (const float*)d_in[5];
  const float* Wo   = (const float*)d_in[6];
  const float* ao1  = (const float*)d_in[7];
  const float* ao2  = (const float*)d_in[8];
  const float* W1   = (const float*)d_in[9];
  const float* b1   = (const float*)d_in[10];
  const float* pw   = (const float*)d_in[11];
  const float* W2   = (const float*)d_in[12];
  const float* b2   = (const float*)d_in[13];
  float* out = (float*)d_out;

  char* base = (char*)d_ws;
  size_t off = 0;
  auto alloc = [&](size_t bytes)->char*{
    char* p = base + off;
    off = (off + bytes + 255) & ~(size_t)255;
    return p;
  };
  unsigned long long* adjbits = (unsigned long long*)alloc((size_t)BB*NN*(NN/64)*8); // 2 MB
  _Float16* WhT  = (_Float16*)alloc((size_t)BB*NHEADS*NHID*NN*2);  // 4 MB, [bh][d][i]
  float* f1   = (float*)alloc((size_t)BB*NHEADS*NN*4);
  float* f2   = (float*)alloc((size_t)BB*NHEADS*NN*4);
  float* m1   = (float*)alloc((size_t)BB*NHEADS*NN*4);
  float* l1   = (float*)alloc((size_t)BB*NHEADS*NN*4);
  int*   cnt1 = (int*)  alloc((size_t)BB*NN*4);
  float* h1   = (float*)alloc((size_t)BB*NN*(NHEADS*NHID)*4);      // 8 MB
  _Float16* WhT2 = (_Float16*)alloc((size_t)BB*NCLASS*NN*2);       // 512 KB, [b][d][i]
  float* f1o  = (float*)alloc((size_t)BB*NN*4);
  float* f2o  = (float*)alloc((size_t)BB*NN*4);
  float* m2   = (float*)alloc((size_t)BB*NN*4);
  float* l2   = (float*)alloc((size_t)BB*NN*4);
  int*   cnt2 = (int*)  alloc((size_t)BB*NN*4);
  float* h2   = (float*)alloc((size_t)BB*NN*NCLASS*4);             // 1 MB

  pack_adj<<<BB*NN, 256, 0, stream>>>(adj, adjbits);
  wh_proj2<<<BB*NHEADS*(NN/64), 256, 0, stream>>>(x, W, a1, a2, WhT, f1, f2);
  attn_stats<NHEADS><<<(BB*NN)/4, 256, 0, stream>>>(adjbits, f1, f2, m1, l1, cnt1);
  attn_wsum_mfma<64><<<BB*NHEADS*(NN/32), 256, 0, stream>>>(adjbits, WhT, f1, f2,
                                                            m1, l1, cnt1, h1, NHEADS, NHEADS*NHID);
  out_proj2<<<BB*(NN/64), 256, 0, stream>>>(h1, Wo, ao1, ao2, WhT2, f1o, f2o);
  attn_stats<1><<<(BB*NN)/4, 256, 0, stream>>>(adjbits, f1o, f2o, m2, l2, cnt2);
  attn_wsum_mfma<32><<<BB*(NN/32), 256, 0, stream>>>(adjbits, WhT2, f1o, f2o,
                                                     m2, l2, cnt2, h2, 1, NCLASS);
  classify<<<(BB*KK1)/4, 256, 0, stream>>>(h2, oh, W1, b1, pw, W2, b2, out);
}

// Round 3
// 269.014 us; speedup vs baseline: 2.6797x; 1.3667x over previous
//
#include <hip/hip_runtime.h>
#include <hip/hip_bf16.h>
#include <stdint.h>
#include <math.h>

#define BB 4
#define NN 2048
#define NFEAT 256
#define NHID 64
#define NHEADS 4
#define NCLASS 32
#define KK1 256
#define ALPHA 0.2f

typedef _Float16 f16x8 __attribute__((ext_vector_type(8)));
typedef _Float16 f16x4 __attribute__((ext_vector_type(4)));
typedef float f32x4 __attribute__((ext_vector_type(4)));

__device__ __forceinline__ f16x8 ld8(const _Float16* p){
  f16x8 r;
  *(f16x4*)&r = *(const f16x4*)p;
  *((f16x4*)&r + 1) = *(const f16x4*)(p + 4);
  return r;
}

// ---------------- K0: pack adj int32 -> bitmask + per-row count ---------
__global__ void __launch_bounds__(256) pack_adj(const int* __restrict__ adj,
                                                unsigned long long* __restrict__ bits,
                                                int* __restrict__ cnt){
  __shared__ int csum[4];
  int row = blockIdx.x;                       // b*N + i
  const int* arow = adj + (size_t)row * NN;
  int lane = threadIdx.x & 63, wv = threadIdx.x >> 6;
  int c = 0;
  #pragma unroll
  for (int it=0; it<NN/256; ++it){
    int j = it*256 + threadIdx.x;
    unsigned long long m = __ballot(arow[j] > 0);
    if (lane==0){ bits[(size_t)row*(NN/64) + it*4 + wv] = m; c += __popcll(m); }
  }
  if (lane==0) csum[wv] = c;
  __syncthreads();
  if (threadIdx.x==0) cnt[row] = csum[0]+csum[1]+csum[2]+csum[3];
}

// ---------------- K1: WhT(f16) = (x @ W)^T per head, plus f1/f2 ---------
// block = (bh, 64-row i-chunk). lane = i, wave w owns d-range w*16..+16.
__global__ void __launch_bounds__(256) wh_proj2(const float* __restrict__ x,
        const float* __restrict__ W, const float* __restrict__ a1, const float* __restrict__ a2,
        _Float16* __restrict__ whT, float* __restrict__ f1, float* __restrict__ f2){
  __shared__ __align__(16) float xs[64*65];
  __shared__ float red1[4][64];
  __shared__ float red2[4][64];
  int bh = blockIdx.x >> 5;
  int i0 = (blockIdx.x & 31) * 64;
  int b = bh >> 2, h = bh & 3;
  int tid = threadIdx.x;
  int lane = tid & 63;
  int dbase = __builtin_amdgcn_readfirstlane(tid >> 6) * 16;
  float acc[16];
  #pragma unroll
  for (int dd=0; dd<16; ++dd) acc[dd] = 0.f;
  for (int kc=0; kc<4; ++kc){
    int kb = kc*64;
    __syncthreads();
    #pragma unroll
    for (int t=0; t<4; ++t){
      int row = t*16 + (tid>>4);
      int f4 = (tid&15)*4;
      float4 v = *(const float4*)(x + ((size_t)(b*NN + i0 + row))*NFEAT + kb + f4);
      xs[row*65 + f4 + 0] = v.x;
      xs[row*65 + f4 + 1] = v.y;
      xs[row*65 + f4 + 2] = v.z;
      xs[row*65 + f4 + 3] = v.w;
    }
    __syncthreads();
    const float* Wb = W + (size_t)h*NFEAT*NHID + (size_t)kb*NHID + dbase;
    #pragma unroll 4
    for (int f=0; f<64; ++f){
      float xv = xs[lane*65 + f];
      const float* wr = Wb + f*NHID;
      #pragma unroll
      for (int dd=0; dd<16; ++dd) acc[dd] = fmaf(xv, wr[dd], acc[dd]);
    }
  }
  // epilogue: transposed f16 store + f1/f2 partials
  float p1 = 0.f, p2 = 0.f;
  #pragma unroll
  for (int dd=0; dd<16; ++dd){
    int d = dbase + dd;
    whT[((size_t)bh*NHID + d)*NN + i0 + lane] = (_Float16)acc[dd];
    p1 = fmaf(acc[dd], a1[h*NHID + d], p1);
    p2 = fmaf(acc[dd], a2[h*NHID + d], p2);
  }
  int wv = tid >> 6;
  red1[wv][lane] = p1;
  red2[wv][lane] = p2;
  __syncthreads();
  if (tid < 64){
    float s1 = red1[0][tid]+red1[1][tid]+red1[2][tid]+red1[3][tid];
    float s2 = red2[0][tid]+red2[1][tid]+red2[2][tid]+red2[3][tid];
    f1[(size_t)bh*NN + i0 + tid] = s1;
    f2[(size_t)bh*NN + i0 + tid] = s2;
  }
}

// ---------- K2/K3: dst = elu(softmax(e) @ Wh), fused l, f16 MFMA --------
// M=32 rows/block, K-chunk=64 j. whT is f16 [bh][D][N] (pre-transposed).
// No max subtraction: scores are O(1), exp is safe; masked lanes are 0.
// l = sum of weights accumulated inline (8 threads/row, shfl reduce).
template<int D>
__global__ void __launch_bounds__(256) attn_wsum_fused(
        const unsigned long long* __restrict__ bits,
        const _Float16* __restrict__ whT,
        const float* __restrict__ f1g, const float* __restrict__ f2g,
        const int* __restrict__ cnt_in,
        float* __restrict__ dst, int H, int dstStride){
  const int PITCH = 68;                         // f16 pitch for 64-j chunk
  __shared__ __align__(16) _Float16 whsT[D*PITCH];
  __shared__ __align__(16) _Float16 wts[32*PITCH];
  __shared__ float ils[32];
  int tile = blockIdx.x & 63;
  int bh = blockIdx.x >> 6;
  int b = bh / H, h = bh - b*H;
  int i0 = tile*32;
  int tid = threadIdx.x;
  int lane = tid & 63, wv = tid >> 6;
  int q = lane >> 4, col = lane & 15;
  // weight-phase mapping: 8 threads per row
  int r = tid >> 3;                             // 0..31
  int j8 = (tid & 7) * 8;
  size_t ro = (size_t)bh*NN + i0 + r;
  float f1r = f1g[ro];
  bool  czr = (cnt_in[b*NN + i0 + r] == 0);
  float lacc = 0.f;
  const _Float16* whTg = whT + (size_t)bh*D*NN;
  f32x4 c0 = {0.f,0.f,0.f,0.f}, c1 = {0.f,0.f,0.f,0.f};
  for (int it=0; it<NN/64; ++it){
    __syncthreads();
    // stage B: whsT[d][j] (transposed Wh, f16) from global
    #pragma unroll
    for (int dd=0; dd<D/32; ++dd){
      int d = dd*32 + (tid>>3);
      uint4 v = *(const uint4*)(whTg + (size_t)d*NN + it*64 + j8);
      uint2* dst2 = (uint2*)&whsT[d*PITCH + j8];
      dst2[0] = uint2{v.x, v.y};
      dst2[1] = uint2{v.z, v.w};
    }
    // stage A: weights for 32 rows x 64 j, plus l partial
    {
      unsigned long long bw = bits[((size_t)(b*NN + i0 + r))*(NN/64) + it];
      const float* f2p = f2g + (size_t)bh*NN + it*64 + j8;
      float4 fa = *(const float4*)(f2p);
      float4 fb = *(const float4*)(f2p + 4);
      float fv[8] = {fa.x,fa.y,fa.z,fa.w,fb.x,fb.y,fb.z,fb.w};
      _Float16 wf[8];
      #pragma unroll
      for (int k=0; k<8; ++k){
        float s = f1r + fv[k];
        float e = fmaxf(s, ALPHA*s);
        bool bit = (bw >> (j8 + k)) & 1ull;
        float w = czr ? 1.0f : (bit ? __expf(e) : 0.0f);
        lacc += w;
        wf[k] = (_Float16)w;
      }
      f16x4* wp = (f16x4*)&wts[r*PITCH + j8];
      wp[0] = f16x4{wf[0],wf[1],wf[2],wf[3]};
      wp[1] = f16x4{wf[4],wf[5],wf[6],wf[7]};
    }
    __syncthreads();
    // MFMA phase: 2 K-steps of 32
    #pragma unroll
    for (int ks=0; ks<2; ++ks){
      int kb = ks*32 + q*8;
      if (D == 64){
        f16x8 a0 = ld8(&wts[(0*16 + col)*PITCH + kb]);
        f16x8 a1f = ld8(&wts[(1*16 + col)*PITCH + kb]);
        f16x8 bf = ld8(&whsT[(wv*16 + col)*PITCH + kb]);
        c0 = __builtin_amdgcn_mfma_f32_16x16x32_f16(a0, bf, c0, 0, 0, 0);
        c1 = __builtin_amdgcn_mfma_f32_16x16x32_f16(a1f, bf, c1, 0, 0, 0);
      } else {
        int mt = wv & 1, nt = wv >> 1;
        f16x8 a0 = ld8(&wts[(mt*16 + col)*PITCH + kb]);
        f16x8 bf = ld8(&whsT[(nt*16 + col)*PITCH + kb]);
        c0 = __builtin_amdgcn_mfma_f32_16x16x32_f16(a0, bf, c0, 0, 0, 0);
      }
    }
  }
  // finalize l: reduce the 8 per-row partials (contiguous lanes)
  lacc += __shfl_xor(lacc, 1, 64);
  lacc += __shfl_xor(lacc, 2, 64);
  lacc += __shfl_xor(lacc, 4, 64);
  if ((tid & 7) == 0) ils[r] = 1.0f / lacc;
  __syncthreads();
  // epilogue: scale by 1/l, ELU, store
  if (D == 64){
    int dloc = wv*16 + col;
    #pragma unroll
    for (int mt=0; mt<2; ++mt){
      #pragma unroll
      for (int reg=0; reg<4; ++reg){
        int ir = mt*16 + q*4 + reg;
        float v = (mt==0 ? c0[reg] : c1[reg]) * ils[ir];
        v = v > 0.f ? v : expm1f(v);
        dst[((size_t)(b*NN + i0 + ir))*dstStride + h*D + dloc] = v;
      }
    }
  } else {
    int mt = wv & 1, nt = wv >> 1;
    int dloc = nt*16 + col;
    #pragma unroll
    for (int reg=0; reg<4; ++reg){
      int ir = mt*16 + q*4 + reg;
      float v = c0[reg] * ils[ir];
      v = v > 0.f ? v : expm1f(v);
      dst[((size_t)(b*NN + i0 + ir))*dstStride + h*D + dloc] = v;
    }
  }
}

// ---------------- K3a: Wh2T(f16) = (h1 @ Wo)^T, plus f1o/f2o ------------
__global__ void __launch_bounds__(256) out_proj2(const float* __restrict__ h1,
        const float* __restrict__ Wo, const float* __restrict__ ao1, const float* __restrict__ ao2,
        _Float16* __restrict__ whT2, float* __restrict__ f1o, float* __restrict__ f2o){
  __shared__ __align__(16) float xs[64*65];
  __shared__ float red1[4][64];
  __shared__ float red2[4][64];
  int b = blockIdx.x >> 5;
  int i0 = (blockIdx.x & 31) * 64;
  int tid = threadIdx.x;
  int lane = tid & 63;
  int dbase = __builtin_amdgcn_readfirstlane(tid >> 6) * 8;
  float acc[8];
  #pragma unroll
  for (int dd=0; dd<8; ++dd) acc[dd] = 0.f;
  for (int kc=0; kc<4; ++kc){
    int kb = kc*64;
    __syncthreads();
    #pragma unroll
    for (int t=0; t<4; ++t){
      int row = t*16 + (tid>>4);
      int f4 = (tid&15)*4;
      float4 v = *(const float4*)(h1 + ((size_t)(b*NN + i0 + row))*256 + kb + f4);
      xs[row*65 + f4 + 0] = v.x;
      xs[row*65 + f4 + 1] = v.y;
      xs[row*65 + f4 + 2] = v.z;
      xs[row*65 + f4 + 3] = v.w;
    }
    __syncthreads();
    #pragma unroll 4
    for (int f=0; f<64; ++f){
      float xv = xs[lane*65 + f];
      const float* wr = Wo + (size_t)(kb+f)*NCLASS + dbase;
      #pragma unroll
      for (int dd=0; dd<8; ++dd) acc[dd] = fmaf(xv, wr[dd], acc[dd]);
    }
  }
  float p1 = 0.f, p2 = 0.f;
  #pragma unroll
  for (int dd=0; dd<8; ++dd){
    int d = dbase + dd;
    whT2[((size_t)b*NCLASS + d)*NN + i0 + lane] = (_Float16)acc[dd];
    p1 = fmaf(acc[dd], ao1[d], p1);
    p2 = fmaf(acc[dd], ao2[d], p2);
  }
  int wv = tid >> 6;
  red1[wv][lane] = p1;
  red2[wv][lane] = p2;
  __syncthreads();
  if (tid < 64){
    float s1 = red1[0][tid]+red1[1][tid]+red1[2][tid]+red1[3][tid];
    float s2 = red2[0][tid]+red2[1][tid]+red2[2][tid]+red2[3][tid];
    f1o[(size_t)b*NN + i0 + tid] = s1;
    f2o[(size_t)b*NN + i0 + tid] = s2;
  }
}

// ---------------- K4: gather + Linear + PReLU + Linear ------------------
__global__ void __launch_bounds__(256) classify(const float* __restrict__ h2,
        const int* __restrict__ idcs, const float* __restrict__ W1, const float* __restrict__ b1,
        const float* __restrict__ pw, const float* __restrict__ W2, const float* __restrict__ b2,
        float* __restrict__ out){
  int row = blockIdx.x*4 + (threadIdx.x>>6);  // 0..B*K1-1
  int lane = threadIdx.x & 63;
  int b = row >> 8;                 // K1 = 256
  int k = row & 255;
  int idx = idcs[b*KK1 + k];
  const float* ef = h2 + ((size_t)b*NN + idx)*NCLASS;
  int c = lane & 31;
  float y = b1[c];
  #pragma unroll 8
  for (int kk=0; kk<32; ++kk) y += ef[kk] * W1[kk*32 + c];
  y = y > 0.f ? y : pw[c]*y;        // PReLU
  float o0 = y * W2[c*2+0];
  float o1 = y * W2[c*2+1];
  #pragma unroll
  for (int o=16;o>0;o>>=1){ o0 += __shfl_xor(o0,o,64); o1 += __shfl_xor(o1,o,64); }
  if (lane==0){ out[row*2+0] = o0 + b2[0]; out[row*2+1] = o1 + b2[1]; }
}

extern "C" void kernel_launch(void* const* d_in, const int* in_sizes, int n_in,
                              void* d_out, int out_size, void* d_ws, size_t ws_size,
                              hipStream_t stream) {
  const float* x    = (const float*)d_in[0];
  const int*   adj  = (const int*)  d_in[1];
  const int*   oh   = (const int*)  d_in[2];
  const float* W    = (const float*)d_in[3];
  const float* a1   = (const float*)d_in[4];
  const float* a2   = (const float*)d_in[5];
  const float* Wo   = (const float*)d_in[6];
  const float* ao1  = (const float*)d_in[7];
  const float* ao2  = (const float*)d_in[8];
  const float* W1   = (const float*)d_in[9];
  const float* b1   = (const float*)d_in[10];
  const float* pw   = (const float*)d_in[11];
  const float* W2   = (const float*)d_in[12];
  const float* b2   = (const float*)d_in[13];
  float* out = (float*)d_out;

  char* base = (char*)d_ws;
  size_t off = 0;
  auto alloc = [&](size_t bytes)->char*{
    char* p = base + off;
    off = (off + bytes + 255) & ~(size_t)255;
    return p;
  };
  unsigned long long* adjbits = (unsigned long long*)alloc((size_t)BB*NN*(NN/64)*8); // 2 MB
  int*   cnt1 = (int*)  alloc((size_t)BB*NN*4);
  _Float16* WhT  = (_Float16*)alloc((size_t)BB*NHEADS*NHID*NN*2);  // 4 MB, [bh][d][i]
  float* f1   = (float*)alloc((size_t)BB*NHEADS*NN*4);
  float* f2   = (float*)alloc((size_t)BB*NHEADS*NN*4);
  float* h1   = (float*)alloc((size_t)BB*NN*(NHEADS*NHID)*4);      // 8 MB
  _Float16* WhT2 = (_Float16*)alloc((size_t)BB*NCLASS*NN*2);       // 512 KB, [b][d][i]
  float* f1o  = (float*)alloc((size_t)BB*NN*4);
  float* f2o  = (float*)alloc((size_t)BB*NN*4);
  float* h2   = (float*)alloc((size_t)BB*NN*NCLASS*4);             // 1 MB

  pack_adj<<<BB*NN, 256, 0, stream>>>(adj, adjbits, cnt1);
  wh_proj2<<<BB*NHEADS*(NN/64), 256, 0, stream>>>(x, W, a1, a2, WhT, f1, f2);
  attn_wsum_fused<64><<<BB*NHEADS*(NN/32), 256, 0, stream>>>(adjbits, WhT, f1, f2,
                                                             cnt1, h1, NHEADS, NHEADS*NHID);
  out_proj2<<<BB*(NN/64), 256, 0, stream>>>(h1, Wo, ao1, ao2, WhT2, f1o, f2o);
  attn_wsum_fused<32><<<BB*(NN/32), 256, 0, stream>>>(adjbits, WhT2, f1o, f2o,
                                                      cnt1, h2, 1, NCLASS);
  classify<<<(BB*KK1)/4, 256, 0, stream>>>(h2, oh, W1, b1, pw, W2, b2, out);
}

// Round 5
// 223.720 us; speedup vs baseline: 3.2222x; 1.2025x over previous
//
#include <hip/hip_runtime.h>
#include <hip/hip_bf16.h>
#include <stdint.h>
#include <math.h>

#define BB 4
#define NN 2048
#define NFEAT 256
#define NHID 64
#define NHEADS 4
#define NCLASS 32
#define KK1 256
#define ALPHA 0.2f
#define LOG2E 1.4426950408889634f

typedef _Float16 f16x8 __attribute__((ext_vector_type(8)));
typedef _Float16 f16x4 __attribute__((ext_vector_type(4)));
typedef _Float16 h16x2 __attribute__((ext_vector_type(2)));
typedef float f32x4 __attribute__((ext_vector_type(4)));

__device__ __forceinline__ f16x8 ld8(const _Float16* p){
  f16x8 r;
  *(f16x4*)&r = *(const f16x4*)p;
  *((f16x4*)&r + 1) = *(const f16x4*)(p + 4);
  return r;
}

__device__ __forceinline__ h16x2 pk2(float a, float b){
  auto v = __builtin_amdgcn_cvt_pkrtz(a, b);   // __fp16 x2
  h16x2 r;
  __builtin_memcpy(&r, &v, sizeof(r));
  return r;
}

// ---------------- K0: pack adj int32 -> bitmask + per-row count ---------
__global__ void __launch_bounds__(256) pack_adj(const int* __restrict__ adj,
                                                unsigned long long* __restrict__ bits,
                                                int* __restrict__ cnt){
  __shared__ int csum[4];
  int row = blockIdx.x;                       // b*N + i
  const int* arow = adj + (size_t)row * NN;
  int lane = threadIdx.x & 63, wv = threadIdx.x >> 6;
  int c = 0;
  #pragma unroll
  for (int it=0; it<NN/256; ++it){
    int j = it*256 + threadIdx.x;
    unsigned long long m = __ballot(arow[j] > 0);
    if (lane==0){ bits[(size_t)row*(NN/64) + it*4 + wv] = m; c += __popcll(m); }
  }
  if (lane==0) csum[wv] = c;
  __syncthreads();
  if (threadIdx.x==0) cnt[row] = csum[0]+csum[1]+csum[2]+csum[3];
}

// ---------------- K1: WhT(f16) = (x @ W)^T per head, f1l/f2l (log2e) ----
__global__ void __launch_bounds__(256) wh_proj2(const float* __restrict__ x,
        const float* __restrict__ W, const float* __restrict__ a1, const float* __restrict__ a2,
        _Float16* __restrict__ whT, float* __restrict__ f1l, float* __restrict__ f2l){
  __shared__ __align__(16) float xs[64*65];
  __shared__ float red1[4][64];
  __shared__ float red2[4][64];
  int bh = blockIdx.x >> 5;
  int i0 = (blockIdx.x & 31) * 64;
  int b = bh >> 2, h = bh & 3;
  int tid = threadIdx.x;
  int lane = tid & 63;
  int dbase = __builtin_amdgcn_readfirstlane(tid >> 6) * 16;
  float acc[16];
  #pragma unroll
  for (int dd=0; dd<16; ++dd) acc[dd] = 0.f;
  for (int kc=0; kc<4; ++kc){
    int kb = kc*64;
    __syncthreads();
    #pragma unroll
    for (int t=0; t<4; ++t){
      int row = t*16 + (tid>>4);
      int f4 = (tid&15)*4;
      float4 v = *(const float4*)(x + ((size_t)(b*NN + i0 + row))*NFEAT + kb + f4);
      xs[row*65 + f4 + 0] = v.x;
      xs[row*65 + f4 + 1] = v.y;
      xs[row*65 + f4 + 2] = v.z;
      xs[row*65 + f4 + 3] = v.w;
    }
    __syncthreads();
    const float* Wb = W + (size_t)h*NFEAT*NHID + (size_t)kb*NHID + dbase;
    #pragma unroll 4
    for (int f=0; f<64; ++f){
      float xv = xs[lane*65 + f];
      const float* wr = Wb + f*NHID;
      #pragma unroll
      for (int dd=0; dd<16; ++dd) acc[dd] = fmaf(xv, wr[dd], acc[dd]);
    }
  }
  float p1 = 0.f, p2 = 0.f;
  #pragma unroll
  for (int dd=0; dd<16; ++dd){
    int d = dbase + dd;
    whT[((size_t)bh*NHID + d)*NN + i0 + lane] = (_Float16)acc[dd];
    p1 = fmaf(acc[dd], a1[h*NHID + d], p1);
    p2 = fmaf(acc[dd], a2[h*NHID + d], p2);
  }
  int wv = tid >> 6;
  red1[wv][lane] = p1;
  red2[wv][lane] = p2;
  __syncthreads();
  if (tid < 64){
    float s1 = red1[0][tid]+red1[1][tid]+red1[2][tid]+red1[3][tid];
    float s2 = red2[0][tid]+red2[1][tid]+red2[2][tid]+red2[3][tid];
    f1l[(size_t)bh*NN + i0 + tid] = s1 * LOG2E;
    f2l[(size_t)bh*NN + i0 + tid] = s2 * LOG2E;
  }
}

// ---------- K2: h1 = elu(softmax(e) @ Wh), fused l, f16 MFMA ------------
// M=32 rows/block, j-chunk=128. Weight math in exp2 domain, pre-masked.
__global__ void __launch_bounds__(256) attn_l1(
        const unsigned long long* __restrict__ bits,
        const _Float16* __restrict__ whT,
        const float* __restrict__ f1l, const float* __restrict__ f2l,
        const int* __restrict__ cnt_in,
        float* __restrict__ dst){
  const int JC = 128, PITCH = 132;
  __shared__ __align__(16) _Float16 whs[64*PITCH];   // 16.9 KB
  __shared__ __align__(16) _Float16 wts[32*PITCH];   // 8.4 KB
  __shared__ float ils[32];
  int tile = blockIdx.x & 63;
  int bh = blockIdx.x >> 6;
  int b = bh >> 2, h = bh & 3;
  int i0 = tile*32;
  int tid = threadIdx.x;
  int lane = tid & 63, wv = tid >> 6;
  int q = lane >> 4, col = lane & 15;
  int r = tid >> 3, jg = (tid & 7) * 16;
  float f1r = f1l[(size_t)bh*NN + i0 + r];
  bool czr = (cnt_in[b*NN + i0 + r] == 0);
  const unsigned short* mrow = (const unsigned short*)(bits + ((size_t)(b*NN + i0 + r))*(NN/64));
  const float* f2p = f2l + (size_t)bh*NN;
  const _Float16* whg = whT + (size_t)bh*NHID*NN;
  float lacc = 0.f;
  f32x4 c0 = {0.f,0.f,0.f,0.f}, c1 = {0.f,0.f,0.f,0.f};
  for (int it=0; it<NN/JC; ++it){
    __syncthreads();
    // stage B: 64 d x 128 j f16 (16 KB)
    #pragma unroll
    for (int dd=0; dd<4; ++dd){
      int d = (tid>>4) + dd*16;
      int j8 = (tid&15)*8;
      uint4 v = *(const uint4*)(whg + (size_t)d*NN + it*JC + j8);
      uint2* w2 = (uint2*)&whs[d*PITCH + j8];
      w2[0] = uint2{v.x, v.y};
      w2[1] = uint2{v.z, v.w};
    }
    // weights: 32 rows x 128 j; 8 threads/row, 16 j each
    {
      unsigned int m16 = mrow[it*8 + (tid&7)];
      const float* fp = f2p + it*JC + jg;
      float4 fa = *(const float4*)(fp);
      float4 fb = *(const float4*)(fp+4);
      float4 fc = *(const float4*)(fp+8);
      float4 fd = *(const float4*)(fp+12);
      float fv[16] = {fa.x,fa.y,fa.z,fa.w, fb.x,fb.y,fb.z,fb.w,
                      fc.x,fc.y,fc.z,fc.w, fd.x,fd.y,fd.z,fd.w};
      h16x2 wp[8];
      #pragma unroll
      for (int p=0; p<8; ++p){
        float s0 = f1r + fv[2*p];
        float s1 = f1r + fv[2*p+1];
        s0 = (m16 & (1u<<(2*p)))   ? s0 : -1e5f;
        s1 = (m16 & (1u<<(2*p+1))) ? s1 : -1e5f;
        float e0 = fmaxf(s0, ALPHA*s0);
        float e1 = fmaxf(s1, ALPHA*s1);
        float w0 = exp2f(e0);
        float w1 = exp2f(e1);
        lacc += w0 + w1;
        wp[p] = pk2(w0, w1);
      }
      if (__builtin_expect(czr, 0)){
        h16x2 one2 = {(_Float16)1.f, (_Float16)1.f};
        #pragma unroll
        for (int p=0; p<8; ++p) wp[p] = one2;
      }
      uint2* wdst = (uint2*)&wts[r*PITCH + jg];
      const uint2* wsrc = (const uint2*)&wp[0];
      wdst[0]=wsrc[0]; wdst[1]=wsrc[1]; wdst[2]=wsrc[2]; wdst[3]=wsrc[3];
    }
    __syncthreads();
    // MFMA: wave wv = n-tile, 2 m-tiles, 4 k-steps
    #pragma unroll
    for (int ks=0; ks<4; ++ks){
      int kb = ks*32 + q*8;
      f16x8 a0 = ld8(&wts[col*PITCH + kb]);
      f16x8 a1v = ld8(&wts[(16+col)*PITCH + kb]);
      f16x8 bv = ld8(&whs[(wv*16+col)*PITCH + kb]);
      c0 = __builtin_amdgcn_mfma_f32_16x16x32_f16(a0, bv, c0, 0, 0, 0);
      c1 = __builtin_amdgcn_mfma_f32_16x16x32_f16(a1v, bv, c1, 0, 0, 0);
    }
  }
  lacc += __shfl_xor(lacc, 1, 64);
  lacc += __shfl_xor(lacc, 2, 64);
  lacc += __shfl_xor(lacc, 4, 64);
  if ((tid & 7) == 0) ils[r] = czr ? (1.0f/(float)NN) : 1.0f/lacc;
  __syncthreads();
  int dloc = wv*16 + col;
  #pragma unroll
  for (int mt=0; mt<2; ++mt){
    #pragma unroll
    for (int reg=0; reg<4; ++reg){
      int ir = mt*16 + q*4 + reg;
      float v = (mt==0 ? c0[reg] : c1[reg]) * ils[ir];
      v = v > 0.f ? v : expm1f(v);
      dst[((size_t)(b*NN + i0 + ir))*(NHEADS*NHID) + h*NHID + dloc] = v;
    }
  }
}

// ---------------- K3a: Wh2T(f16) = (h1 @ Wo)^T, f1ol/f2ol (log2e) -------
__global__ void __launch_bounds__(256) out_proj2(const float* __restrict__ h1,
        const float* __restrict__ Wo, const float* __restrict__ ao1, const float* __restrict__ ao2,
        _Float16* __restrict__ whT2, float* __restrict__ f1ol, float* __restrict__ f2ol){
  __shared__ __align__(16) float xs[64*65];
  __shared__ float red1[4][64];
  __shared__ float red2[4][64];
  int b = blockIdx.x >> 5;
  int i0 = (blockIdx.x & 31) * 64;
  int tid = threadIdx.x;
  int lane = tid & 63;
  int dbase = __builtin_amdgcn_readfirstlane(tid >> 6) * 8;
  float acc[8];
  #pragma unroll
  for (int dd=0; dd<8; ++dd) acc[dd] = 0.f;
  for (int kc=0; kc<4; ++kc){
    int kb = kc*64;
    __syncthreads();
    #pragma unroll
    for (int t=0; t<4; ++t){
      int row = t*16 + (tid>>4);
      int f4 = (tid&15)*4;
      float4 v = *(const float4*)(h1 + ((size_t)(b*NN + i0 + row))*256 + kb + f4);
      xs[row*65 + f4 + 0] = v.x;
      xs[row*65 + f4 + 1] = v.y;
      xs[row*65 + f4 + 2] = v.z;
      xs[row*65 + f4 + 3] = v.w;
    }
    __syncthreads();
    #pragma unroll 4
    for (int f=0; f<64; ++f){
      float xv = xs[lane*65 + f];
      const float* wr = Wo + (size_t)(kb+f)*NCLASS + dbase;
      #pragma unroll
      for (int dd=0; dd<8; ++dd) acc[dd] = fmaf(xv, wr[dd], acc[dd]);
    }
  }
  float p1 = 0.f, p2 = 0.f;
  #pragma unroll
  for (int dd=0; dd<8; ++dd){
    int d = dbase + dd;
    whT2[((size_t)b*NCLASS + d)*NN + i0 + lane] = (_Float16)acc[dd];
    p1 = fmaf(acc[dd], ao1[d], p1);
    p2 = fmaf(acc[dd], ao2[d], p2);
  }
  int wv = tid >> 6;
  red1[wv][lane] = p1;
  red2[wv][lane] = p2;
  __syncthreads();
  if (tid < 64){
    float s1 = red1[0][tid]+red1[1][tid]+red1[2][tid]+red1[3][tid];
    float s2 = red2[0][tid]+red2[1][tid]+red2[2][tid]+red2[3][tid];
    f1ol[(size_t)b*NN + i0 + tid] = s1 * LOG2E;
    f2ol[(size_t)b*NN + i0 + tid] = s2 * LOG2E;
  }
}

// ---------- K3b: layer-2 attention, GATHERED rows only, j-split x8 ------
// block = (b, kt, js): 32 gathered rows, j range [js*256, +256) (2 iters).
// Writes partial c [blk][32][32] and partial l [blk][32].
__global__ void __launch_bounds__(256) attn_l2(
        const unsigned long long* __restrict__ bits,
        const _Float16* __restrict__ whT2,
        const float* __restrict__ f1ol, const float* __restrict__ f2ol,
        const int* __restrict__ cnt_in, const int* __restrict__ oh,
        float* __restrict__ pc, float* __restrict__ pl){
  const int JC = 128, PITCH = 132;
  __shared__ __align__(16) _Float16 whs[32*PITCH];
  __shared__ __align__(16) _Float16 wts[32*PITCH];
  int blk = blockIdx.x;
  int js = blk & 7, kt = (blk>>3) & 7, b = blk >> 6;
  int tid = threadIdx.x;
  int lane = tid & 63, wv = tid >> 6;
  int q = lane >> 4, col = lane & 15;
  int r = tid >> 3, jg = (tid & 7) * 16;
  int row_i = oh[b*KK1 + kt*32 + r];
  float f1r = f1ol[b*NN + row_i];
  bool czr = (cnt_in[b*NN + row_i] == 0);
  const unsigned short* mrow = (const unsigned short*)(bits + ((size_t)(b*NN + row_i))*(NN/64));
  const float* f2p = f2ol + (size_t)b*NN;
  const _Float16* whg = whT2 + (size_t)b*NCLASS*NN;
  float lacc = 0.f;
  f32x4 c0 = {0.f,0.f,0.f,0.f};
  int mt = wv & 1, nt = wv >> 1;
  for (int ii=0; ii<2; ++ii){
    int it = js*2 + ii;
    __syncthreads();
    #pragma unroll
    for (int dd=0; dd<2; ++dd){
      int d = (tid>>4) + dd*16;
      int j8 = (tid&15)*8;
      uint4 v = *(const uint4*)(whg + (size_t)d*NN + it*JC + j8);
      uint2* w2 = (uint2*)&whs[d*PITCH + j8];
      w2[0] = uint2{v.x, v.y};
      w2[1] = uint2{v.z, v.w};
    }
    {
      unsigned int m16 = mrow[it*8 + (tid&7)];
      const float* fp = f2p + it*JC + jg;
      float4 fa = *(const float4*)(fp);
      float4 fb = *(const float4*)(fp+4);
      float4 fc = *(const float4*)(fp+8);
      float4 fd = *(const float4*)(fp+12);
      float fv[16] = {fa.x,fa.y,fa.z,fa.w, fb.x,fb.y,fb.z,fb.w,
                      fc.x,fc.y,fc.z,fc.w, fd.x,fd.y,fd.z,fd.w};
      h16x2 wp[8];
      #pragma unroll
      for (int p=0; p<8; ++p){
        float s0 = f1r + fv[2*p];
        float s1 = f1r + fv[2*p+1];
        s0 = (m16 & (1u<<(2*p)))   ? s0 : -1e5f;
        s1 = (m16 & (1u<<(2*p+1))) ? s1 : -1e5f;
        float e0 = fmaxf(s0, ALPHA*s0);
        float e1 = fmaxf(s1, ALPHA*s1);
        float w0 = exp2f(e0);
        float w1 = exp2f(e1);
        lacc += w0 + w1;
        wp[p] = pk2(w0, w1);
      }
      if (__builtin_expect(czr, 0)){
        h16x2 one2 = {(_Float16)1.f, (_Float16)1.f};
        #pragma unroll
        for (int p=0; p<8; ++p) wp[p] = one2;
        lacc += 16.f;
      }
      uint2* wdst = (uint2*)&wts[r*PITCH + jg];
      const uint2* wsrc = (const uint2*)&wp[0];
      wdst[0]=wsrc[0]; wdst[1]=wsrc[1]; wdst[2]=wsrc[2]; wdst[3]=wsrc[3];
    }
    __syncthreads();
    #pragma unroll
    for (int ks=0; ks<4; ++ks){
      int kb = ks*32 + q*8;
      f16x8 a0 = ld8(&wts[(mt*16+col)*PITCH + kb]);
      f16x8 bv = ld8(&whs[(nt*16+col)*PITCH + kb]);
      c0 = __builtin_amdgcn_mfma_f32_16x16x32_f16(a0, bv, c0, 0, 0, 0);
    }
  }
  lacc += __shfl_xor(lacc, 1, 64);
  lacc += __shfl_xor(lacc, 2, 64);
  lacc += __shfl_xor(lacc, 4, 64);
  if ((tid & 7) == 0) pl[blk*32 + r] = lacc;
  int dloc = nt*16 + col;
  #pragma unroll
  for (int reg=0; reg<4; ++reg){
    int ir = mt*16 + q*4 + reg;
    pc[(size_t)blk*1024 + ir*32 + dloc] = c0[reg];
  }
}

// ---------------- K4: combine partials + ELU + MLP ----------------------
__global__ void __launch_bounds__(256) classify2(const float* __restrict__ pc,
        const float* __restrict__ pl,
        const float* __restrict__ W1, const float* __restrict__ b1,
        const float* __restrict__ pw, const float* __restrict__ W2, const float* __restrict__ b2,
        float* __restrict__ out){
  __shared__ float efs[4][32];
  int wv = threadIdx.x >> 6;
  int lane = threadIdx.x & 63;
  int row = blockIdx.x*4 + wv;        // 0..B*K1-1
  int b = row >> 8, k = row & 255;
  int kt = k >> 5, r = k & 31;
  int base = (b*8 + kt)*8;
  if (lane < 32){
    float s = 0.f, l = 0.f;
    #pragma unroll
    for (int js=0; js<8; ++js){
      s += pc[(size_t)(base+js)*1024 + r*32 + lane];
      l += pl[(base+js)*32 + r];
    }
    float v = s / l;
    v = v > 0.f ? v : expm1f(v);
    efs[wv][lane] = v;
  }
  __syncthreads();
  const float* ef = efs[wv];
  int c = lane & 31;
  float y = b1[c];
  #pragma unroll 8
  for (int kk=0; kk<32; ++kk) y += ef[kk] * W1[kk*32 + c];
  y = y > 0.f ? y : pw[c]*y;
  float o0 = y * W2[c*2+0];
  float o1 = y * W2[c*2+1];
  #pragma unroll
  for (int o=16;o>0;o>>=1){ o0 += __shfl_xor(o0,o,64); o1 += __shfl_xor(o1,o,64); }
  if (lane==0){ out[row*2+0] = o0 + b2[0]; out[row*2+1] = o1 + b2[1]; }
}

extern "C" void kernel_launch(void* const* d_in, const int* in_sizes, int n_in,
                              void* d_out, int out_size, void* d_ws, size_t ws_size,
                              hipStream_t stream) {
  const float* x    = (const float*)d_in[0];
  const int*   adj  = (const int*)  d_in[1];
  const int*   oh   = (const int*)  d_in[2];
  const float* W    = (const float*)d_in[3];
  const float* a1   = (const float*)d_in[4];
  const float* a2   = (const float*)d_in[5];
  const float* Wo   = (const float*)d_in[6];
  const float* ao1  = (const float*)d_in[7];
  const float* ao2  = (const float*)d_in[8];
  const float* W1   = (const float*)d_in[9];
  const float* b1   = (const float*)d_in[10];
  const float* pw   = (const float*)d_in[11];
  const float* W2   = (const float*)d_in[12];
  const float* b2   = (const float*)d_in[13];
  float* out = (float*)d_out;

  char* base = (char*)d_ws;
  size_t off = 0;
  auto alloc = [&](size_t bytes)->char*{
    char* p = base + off;
    off = (off + bytes + 255) & ~(size_t)255;
    return p;
  };
  unsigned long long* adjbits = (unsigned long long*)alloc((size_t)BB*NN*(NN/64)*8); // 2 MB
  int*   cnt1 = (int*)  alloc((size_t)BB*NN*4);
  _Float16* WhT  = (_Float16*)alloc((size_t)BB*NHEADS*NHID*NN*2);  // 4 MB, [bh][d][i]
  float* f1l  = (float*)alloc((size_t)BB*NHEADS*NN*4);
  float* f2l  = (float*)alloc((size_t)BB*NHEADS*NN*4);
  float* h1   = (float*)alloc((size_t)BB*NN*(NHEADS*NHID)*4);      // 8 MB
  _Float16* WhT2 = (_Float16*)alloc((size_t)BB*NCLASS*NN*2);       // 512 KB, [b][d][i]
  float* f1ol = (float*)alloc((size_t)BB*NN*4);
  float* f2ol = (float*)alloc((size_t)BB*NN*4);
  float* pc   = (float*)alloc((size_t)256*1024*4);                 // 1 MB partial c
  float* pl   = (float*)alloc((size_t)256*32*4);                   // partial l

  pack_adj<<<BB*NN, 256, 0, stream>>>(adj, adjbits, cnt1);
  wh_proj2<<<BB*NHEADS*(NN/64), 256, 0, stream>>>(x, W, a1, a2, WhT, f1l, f2l);
  attn_l1<<<BB*NHEADS*(NN/32), 256, 0, stream>>>(adjbits, WhT, f1l, f2l, cnt1, h1);
  out_proj2<<<BB*(NN/64), 256, 0, stream>>>(h1, Wo, ao1, ao2, WhT2, f1ol, f2ol);
  attn_l2<<<BB*8*8, 256, 0, stream>>>(adjbits, WhT2, f1ol, f2ol, cnt1, oh, pc, pl);
  classify2<<<(BB*KK1)/4, 256, 0, stream>>>(pc, pl, W1, b1, pw, W2, b2, out);
}